// Round 8
// baseline (47801.895 us; speedup 1.0000x reference)
//
#include <hip/hip_runtime.h>
#include <hip/hip_bf16.h>
#include <math.h>

#define BZ 256
#define MCN 128
#define HS 768
#define NC 7
#define LED 128
#define G4 3072
#define LDP (LED + 2 * HS)   // 1664

#define TBM 64
#define TBN 64
#define TBK 16

__device__ __forceinline__ ushort f2bf(float f) {
    uint x = __float_as_uint(f);
    uint r = (x + 0x7fffu + ((x >> 16) & 1u)) >> 16;   // RNE
    return (ushort)r;
}
__device__ __forceinline__ float bf2f(ushort u) {
    return __uint_as_float(((uint)u) << 16);
}

// ================= generic tiled GEMMs (precompute only) =================
// C[M,N] = A[M,K] @ B[N,K]^T (+bias[N]) ; Cbf!=null -> bf16 output
__global__ __launch_bounds__(256) void gemm_abt(
    const float* __restrict__ A, int lda,
    const float* __restrict__ B, int ldb,
    const float* __restrict__ bias,
    float* __restrict__ C, ushort* __restrict__ Cbf, int ldc, int K)
{
    __shared__ float As[TBK][TBM + 4];
    __shared__ float Bs[TBK][TBN + 4];
    const int tid = threadIdx.x;
    const int m0 = blockIdx.y * TBM;
    const int n0 = blockIdx.x * TBN;
    const int tx = tid & 15, ty = tid >> 4;
    const int lrow = tid >> 2;
    const int lcol = (tid & 3) * 4;
    float acc[4][4] = {};
    const float* Ap = A + (size_t)(m0 + lrow) * lda + lcol;
    const float* Bp = B + (size_t)(n0 + lrow) * ldb + lcol;
    for (int k0 = 0; k0 < K; k0 += TBK) {
        float4 av = *(const float4*)(Ap + k0);
        float4 bv = *(const float4*)(Bp + k0);
        As[lcol + 0][lrow] = av.x; As[lcol + 1][lrow] = av.y;
        As[lcol + 2][lrow] = av.z; As[lcol + 3][lrow] = av.w;
        Bs[lcol + 0][lrow] = bv.x; Bs[lcol + 1][lrow] = bv.y;
        Bs[lcol + 2][lrow] = bv.z; Bs[lcol + 3][lrow] = bv.w;
        __syncthreads();
        #pragma unroll
        for (int kk = 0; kk < TBK; ++kk) {
            float4 a4 = *(const float4*)&As[kk][ty * 4];
            float4 b4 = *(const float4*)&Bs[kk][tx * 4];
            float a[4] = {a4.x, a4.y, a4.z, a4.w};
            float b[4] = {b4.x, b4.y, b4.z, b4.w};
            #pragma unroll
            for (int i = 0; i < 4; ++i)
                #pragma unroll
                for (int j = 0; j < 4; ++j)
                    acc[i][j] += a[i] * b[j];
        }
        __syncthreads();
    }
    #pragma unroll
    for (int i = 0; i < 4; ++i) {
        int m = m0 + ty * 4 + i;
        #pragma unroll
        for (int j = 0; j < 4; ++j) {
            float v = acc[i][j];
            if (bias) v += bias[n0 + tx * 4 + j];
            if (Cbf) Cbf[(size_t)m * ldc + n0 + tx * 4 + j] = f2bf(v);
            else     C  [(size_t)m * ldc + n0 + tx * 4 + j] = v;
        }
    }
}

// C[M,N] = A[M,K] @ B[K,N] ; Cbf!=null -> bf16 output
__global__ __launch_bounds__(256) void gemm_ab(
    const float* __restrict__ A, int lda,
    const float* __restrict__ B, int ldb,
    float* __restrict__ C, ushort* __restrict__ Cbf, int ldc, int K)
{
    __shared__ float As[TBK][TBM + 4];
    __shared__ float Bs[TBK][TBN + 4];
    const int tid = threadIdx.x;
    const int m0 = blockIdx.y * TBM, n0 = blockIdx.x * TBN;
    const int tx = tid & 15, ty = tid >> 4;
    float acc[4][4] = {};
    for (int k0 = 0; k0 < K; k0 += TBK) {
        #pragma unroll
        for (int i = 0; i < 4; ++i) {
            int idx = tid + i * 256;
            int r = idx >> 4, kk = idx & 15;
            As[kk][r] = A[(size_t)(m0 + r) * lda + k0 + kk];
        }
        #pragma unroll
        for (int i = 0; i < 4; ++i) {
            int idx = tid + i * 256;
            int kk = idx >> 6, cc = idx & 63;
            Bs[kk][cc] = B[(size_t)(k0 + kk) * ldb + n0 + cc];
        }
        __syncthreads();
        #pragma unroll
        for (int kk = 0; kk < TBK; ++kk) {
            float4 a4 = *(const float4*)&As[kk][ty * 4];
            float4 b4 = *(const float4*)&Bs[kk][tx * 4];
            float a[4] = {a4.x, a4.y, a4.z, a4.w};
            float b[4] = {b4.x, b4.y, b4.z, b4.w};
            #pragma unroll
            for (int i = 0; i < 4; ++i)
                #pragma unroll
                for (int j = 0; j < 4; ++j)
                    acc[i][j] += a[i] * b[j];
        }
        __syncthreads();
    }
    #pragma unroll
    for (int i = 0; i < 4; ++i) {
        int m = m0 + ty * 4 + i;
        #pragma unroll
        for (int j = 0; j < 4; ++j) {
            float v = acc[i][j];
            if (Cbf) Cbf[(size_t)m * ldc + n0 + tx * 4 + j] = f2bf(v);
            else     C  [(size_t)m * ldc + n0 + tx * 4 + j] = v;
        }
    }
}

// C[M,N] = alpha * A^T @ B : A[K,M], B[K,N]
__global__ __launch_bounds__(256) void gemm_atb(
    const float* __restrict__ A, int lda,
    const float* __restrict__ B, int ldb,
    float* __restrict__ C, int ldc, int K, float alpha)
{
    __shared__ float As[TBK][TBM + 4];
    __shared__ float Bs[TBK][TBN + 4];
    const int tid = threadIdx.x;
    const int m0 = blockIdx.y * TBM, n0 = blockIdx.x * TBN;
    const int tx = tid & 15, ty = tid >> 4;
    float acc[4][4] = {};
    for (int k0 = 0; k0 < K; k0 += TBK) {
        #pragma unroll
        for (int i = 0; i < 4; ++i) {
            int idx = tid + i * 256;
            int kk = idx >> 6, r = idx & 63;
            As[kk][r] = A[(size_t)(k0 + kk) * lda + m0 + r];
            Bs[kk][r] = B[(size_t)(k0 + kk) * ldb + n0 + r];
        }
        __syncthreads();
        #pragma unroll
        for (int kk = 0; kk < TBK; ++kk) {
            float4 a4 = *(const float4*)&As[kk][ty * 4];
            float4 b4 = *(const float4*)&Bs[kk][tx * 4];
            float a[4] = {a4.x, a4.y, a4.z, a4.w};
            float b[4] = {b4.x, b4.y, b4.z, b4.w};
            #pragma unroll
            for (int i = 0; i < 4; ++i)
                #pragma unroll
                for (int j = 0; j < 4; ++j)
                    acc[i][j] += a[i] * b[j];
        }
        __syncthreads();
    }
    #pragma unroll
    for (int i = 0; i < 4; ++i) {
        float* Cr = C + (size_t)(m0 + ty * 4 + i) * ldc + n0 + tx * 4;
        #pragma unroll
        for (int j = 0; j < 4; ++j) Cr[j] = alpha * acc[i][j];
    }
}

// ================= fused per-step attention (bf16 K'/V') =================
__global__ __launch_bounds__(768) void attn_step(
    const float* __restrict__ h1, const ushort* __restrict__ Kp,
    const ushort* __restrict__ Vp, const float* __restrict__ cmask,
    const float* __restrict__ lng, const float* __restrict__ lnb,
    const float* __restrict__ bo,
    const float* __restrict__ Wout, const float* __restrict__ bout,
    float* __restrict__ out, float* __restrict__ attn_out, int t)
{
    __shared__ float hs[HS];
    __shared__ float sc[MCN];
    __shared__ float red[12];
    const int b = blockIdx.x, tid = threadIdx.x;
    const int lane = tid & 63, wv = tid >> 6;   // 12 waves
    hs[tid] = h1[(size_t)b * HS + tid];
    __syncthreads();
    if (t > 0 && wv < NC) {
        const float* wr = Wout + (size_t)wv * HS;
        float s = 0.f;
        #pragma unroll
        for (int k = lane; k < HS; k += 64) s += hs[k] * wr[k];
        #pragma unroll
        for (int o = 32; o; o >>= 1) s += __shfl_down(s, o);
        if (lane == 0) out[((size_t)b * MCN + (t - 1)) * NC + wv] = s + bout[wv];
    }
    const ushort* Kb = Kp + (size_t)b * MCN * HS;
    for (int m = wv; m < MCN; m += 12) {
        const ushort* kr = Kb + (size_t)m * HS;
        float s = 0.f;
        #pragma unroll
        for (int k = lane * 2; k < HS; k += 128) {
            uint v = *(const uint*)(kr + k);
            s += hs[k] * bf2f((ushort)(v & 0xffffu))
               + hs[k + 1] * bf2f((ushort)(v >> 16));
        }
        #pragma unroll
        for (int o = 32; o; o >>= 1) s += __shfl_down(s, o);
        if (lane == 0) sc[m] = s + cmask[(size_t)b * MCN + m];
    }
    __syncthreads();
    if (tid < 64) {
        float a = sc[tid], c2 = sc[tid + 64];
        float mx = fmaxf(a, c2);
        #pragma unroll
        for (int o = 32; o; o >>= 1) mx = fmaxf(mx, __shfl_down(mx, o));
        mx = __shfl(mx, 0);
        float e0 = expf(a - mx), e1 = expf(c2 - mx);
        float ss = e0 + e1;
        #pragma unroll
        for (int o = 32; o; o >>= 1) ss += __shfl_down(ss, o);
        ss = __shfl(ss, 0);
        float inv = 1.0f / ss;
        sc[tid] = e0 * inv; sc[tid + 64] = e1 * inv;
    }
    __syncthreads();
    const int n = tid;
    const ushort* vp = Vp + (size_t)b * MCN * HS + n;
    float a = 0.f;
    #pragma unroll 8
    for (int m = 0; m < MCN; ++m) a += sc[m] * bf2f(vp[(size_t)m * HS]);
    a += bo[n] + hs[n];
    float lsum = a;
    #pragma unroll
    for (int o = 32; o; o >>= 1) lsum += __shfl_down(lsum, o);
    if (lane == 0) red[wv] = lsum;
    __syncthreads();
    float mu = 0.f;
    #pragma unroll
    for (int i = 0; i < 12; ++i) mu += red[i];
    mu *= (1.0f / HS);
    __syncthreads();
    float d = a - mu;
    float qq = d * d;
    #pragma unroll
    for (int o = 32; o; o >>= 1) qq += __shfl_down(qq, o);
    if (lane == 0) red[wv] = qq;
    __syncthreads();
    float var = 0.f;
    #pragma unroll
    for (int i = 0; i < 12; ++i) var += red[i];
    var *= (1.0f / HS);
    float inv = 1.0f / sqrtf(var + 1e-12f);
    attn_out[(size_t)b * HS + n] = d * inv * lng[n] + lnb[n];
}

// ================= fused LSTM step: up to 3 concat GEMM parts + pointwise =================
// gates[b, s*HS+n] = sum_p A_p[b,:] @ B_p[s*HS+n, :] + pre[s*HS+n] (+emb via tl/T7g)
// block: 32 batch x (32 cols x 4 gates); double-buffered LDS, float4 reads.
__global__ __launch_bounds__(256) void lstm_fused(
    const float* __restrict__ A1, long s1, const void* __restrict__ B1, int f1,
    const float* __restrict__ A2, long s2, const void* __restrict__ B2, int f2,
    const float* __restrict__ A3, long s3, const void* __restrict__ B3, int f3,
    int nparts,
    const float* __restrict__ pre, const float* __restrict__ tl,
    const float* __restrict__ T7g, int t,
    float* __restrict__ cbuf, float* __restrict__ hout)
{
    __shared__ float As[2][TBK][32];        // [buf][kk][batch]
    __shared__ float Bs[2][TBK][32][4];     // [buf][kk][col][gate]
    const int tid = threadIdx.x;
    const int n0 = blockIdx.x * 32;
    const int b0 = blockIdx.y * 32;
    const int nn = tid & 31;
    const int mb = tid >> 5;                // 0..7 -> batches mb*4..mb*4+3
    float acc[4][4] = {};

    const int tiles_per_part = HS / TBK;    // 48
    const int ntile = nparts * tiles_per_part;

    auto stage = [&](int kt, int buf) {
        int p = kt / tiles_per_part;
        int k0 = (kt % tiles_per_part) * TBK;
        const float* A; long as_; const void* B; int bf;
        if (p == 0)      { A = A1; as_ = s1; B = B1; bf = f1; }
        else if (p == 1) { A = A2; as_ = s2; B = B2; bf = f2; }
        else             { A = A3; as_ = s3; B = B3; bf = f3; }
        if (tid < 128) {
            int r = tid >> 2, q = tid & 3;
            float4 av = *(const float4*)(A + (long)(b0 + r) * as_ + k0 + q * 4);
            As[buf][q * 4 + 0][r] = av.x; As[buf][q * 4 + 1][r] = av.y;
            As[buf][q * 4 + 2][r] = av.z; As[buf][q * 4 + 3][r] = av.w;
        }
        #pragma unroll
        for (int rep = 0; rep < 2; ++rep) {
            int idx = tid + rep * 256;
            int nn_ = idx & 31, s_ = (idx >> 5) & 3, q_ = idx >> 7;
            long off = (long)(s_ * HS + n0 + nn_) * HS + k0 + q_ * 4;
            float v0, v1, v2, v3;
            if (bf) {
                uint2 u = *(const uint2*)((const ushort*)B + off);
                v0 = bf2f((ushort)(u.x & 0xffffu)); v1 = bf2f((ushort)(u.x >> 16));
                v2 = bf2f((ushort)(u.y & 0xffffu)); v3 = bf2f((ushort)(u.y >> 16));
            } else {
                float4 bv = *(const float4*)((const float*)B + off);
                v0 = bv.x; v1 = bv.y; v2 = bv.z; v3 = bv.w;
            }
            Bs[buf][q_ * 4 + 0][nn_][s_] = v0; Bs[buf][q_ * 4 + 1][nn_][s_] = v1;
            Bs[buf][q_ * 4 + 2][nn_][s_] = v2; Bs[buf][q_ * 4 + 3][nn_][s_] = v3;
        }
    };

    stage(0, 0);
    int cur = 0;
    for (int kt = 0; kt < ntile; ++kt) {
        __syncthreads();
        if (kt + 1 < ntile) stage(kt + 1, cur ^ 1);
        #pragma unroll
        for (int kk = 0; kk < TBK; ++kk) {
            float4 a4 = *(const float4*)&As[cur][kk][mb * 4];
            float4 b4 = *(const float4*)&Bs[cur][kk][nn][0];
            float av[4] = {a4.x, a4.y, a4.z, a4.w};
            float bv[4] = {b4.x, b4.y, b4.z, b4.w};
            #pragma unroll
            for (int i = 0; i < 4; ++i)
                #pragma unroll
                for (int s = 0; s < 4; ++s)
                    acc[i][s] += av[i] * bv[s];
        }
        cur ^= 1;
    }

    const int n = n0 + nn;
    float pv[4];
    #pragma unroll
    for (int s = 0; s < 4; ++s) pv[s] = pre[s * HS + n];
    float tg[NC][4];
    if (tl) {
        #pragma unroll
        for (int c = 0; c < NC; ++c)
            #pragma unroll
            for (int s = 0; s < 4; ++s)
                tg[c][s] = T7g[(size_t)c * G4 + s * HS + n];
    }
    #pragma unroll
    for (int i = 0; i < 4; ++i) {
        int b = b0 + mb * 4 + i;
        float g0 = acc[i][0] + pv[0];
        float g1 = acc[i][1] + pv[1];
        float g2 = acc[i][2] + pv[2];
        float g3 = acc[i][3] + pv[3];
        if (tl) {
            if (t == 0) {
                g0 += tg[NC - 1][0]; g1 += tg[NC - 1][1];
                g2 += tg[NC - 1][2]; g3 += tg[NC - 1][3];
            } else {
                const float* lp = tl + ((size_t)b * MCN + (t - 1)) * NC;
                #pragma unroll
                for (int c = 0; c < NC; ++c) {
                    float l = lp[c];
                    g0 += l * tg[c][0]; g1 += l * tg[c][1];
                    g2 += l * tg[c][2]; g3 += l * tg[c][3];
                }
            }
        }
        float ig = 1.f / (1.f + expf(-g0));
        float fg = 1.f / (1.f + expf(-g1));
        float gg = tanhf(g2);
        float og = 1.f / (1.f + expf(-g3));
        size_t idx = (size_t)b * HS + n;
        float cn = fg * cbuf[idx] + ig * gg;
        cbuf[idx] = cn;
        hout[idx] = og * tanhf(cn);
    }
}

// ================= small setup / fold kernels =================
__global__ void vec_add2(const float* a, const float* b, float* o)
{
    int i = blockIdx.x * 256 + threadIdx.x;
    if (i < G4) o[i] = a[i] + b[i];
}

__global__ void t7_kernel(const float* __restrict__ LE, const float* __restrict__ Wp,
                          float* __restrict__ T7)
{
    int idx = blockIdx.x * blockDim.x + threadIdx.x;
    if (idx >= NC * HS) return;
    int c = idx / HS, n = idx % HS;
    float s = 0.f;
    for (int d = 0; d < LED; ++d) s += LE[c * LED + d] * Wp[(size_t)n * LDP + d];
    T7[idx] = s;
}

// bkq = scale*(bk@Wq) ; bvo = bv@Wo^T ; kqv = scale*(bq@Wk) ; kqv[HS] = scale*bq.bk
__global__ void fold_vecs(const float* __restrict__ Wq, const float* __restrict__ Wk,
                          const float* __restrict__ Wo,
                          const float* __restrict__ bq, const float* __restrict__ bk,
                          const float* __restrict__ bv,
                          float* __restrict__ bkq, float* __restrict__ bvo,
                          float* __restrict__ kqv, float scale)
{
    int j = blockIdx.x * 256 + threadIdx.x;
    if (j < HS) {
        float s1 = 0.f, s2 = 0.f, s3 = 0.f;
        for (int i = 0; i < HS; ++i) {
            s1 += bk[i] * Wq[(size_t)i * HS + j];
            s2 += bv[i] * Wo[(size_t)j * HS + i];
            s3 += bq[i] * Wk[(size_t)i * HS + j];
        }
        bkq[j] = s1 * scale; bvo[j] = s2; kqv[j] = s3 * scale;
    } else if (j == HS) {
        float s = 0.f;
        for (int i = 0; i < HS; ++i) s += bq[i] * bk[i];
        kqv[HS] = s * scale;
    }
}

__global__ __launch_bounds__(256) void cmask_kernel(
    const float* __restrict__ cv, const float* __restrict__ mask,
    const float* __restrict__ kqv, float* __restrict__ cm)
{
    int row = blockIdx.x * 4 + (threadIdx.x >> 6);
    int lane = threadIdx.x & 63;
    const float* r = cv + (size_t)row * HS;
    float s = 0.f;
    #pragma unroll
    for (int k = lane; k < HS; k += 64) s += r[k] * kqv[k];
    #pragma unroll
    for (int o = 32; o; o >>= 1) s += __shfl_down(s, o);
    if (lane == 0)
        cm[row] = s + kqv[HS] + (1.0f - mask[row]) * (-10000.0f);
}

// T7g[c,g] = T7[c]@Wih0[g] ; bp0[g] = bp@Wih0[g] + bih0[g] + bhh0[g]
__global__ void t7g_bp0(const float* __restrict__ T7, const float* __restrict__ Wih0,
                        const float* __restrict__ bp, const float* __restrict__ bih0,
                        const float* __restrict__ bhh0,
                        float* __restrict__ T7g, float* __restrict__ bp0)
{
    int g = blockIdx.x * 256 + threadIdx.x;
    if (g >= G4) return;
    float acc[NC] = {};
    float ab = 0.f;
    const float* wr = Wih0 + (size_t)g * HS;
    for (int n = 0; n < HS; ++n) {
        float w = wr[n];
        ab += bp[n] * w;
        #pragma unroll
        for (int c = 0; c < NC; ++c) acc[c] += T7[c * HS + n] * w;
    }
    #pragma unroll
    for (int c = 0; c < NC; ++c) T7g[(size_t)c * G4 + g] = acc[c];
    bp0[g] = ab + bih0[g] + bhh0[g];
}

__global__ __launch_bounds__(64) void pred_kernel(
    const float* __restrict__ h1, const float* __restrict__ Wout,
    const float* __restrict__ bout, float* __restrict__ out, int t)
{
    const int b = blockIdx.x, c = blockIdx.y, lane = threadIdx.x;
    const float* hr = h1 + (size_t)b * HS;
    const float* wr = Wout + (size_t)c * HS;
    float s = 0.f;
    #pragma unroll
    for (int k = lane; k < HS; k += 64) s += hr[k] * wr[k];
    #pragma unroll
    for (int o = 32; o; o >>= 1) s += __shfl_down(s, o);
    if (lane == 0) out[((size_t)b * MCN + t) * NC + c] = s + bout[c];
}

// ================= host =================
extern "C" void kernel_launch(void* const* d_in, const int* in_sizes, int n_in,
                              void* d_out, int out_size, void* d_ws, size_t ws_size,
                              hipStream_t stream)
{
    (void)in_sizes; (void)n_in; (void)out_size; (void)ws_size;
    const float* cv   = (const float*)d_in[0];
    const float* mask = (const float*)d_in[1];
    const float* tl   = (const float*)d_in[2];
    const float* LE   = (const float*)d_in[3];
    const float* Wq   = (const float*)d_in[4];  const float* bq  = (const float*)d_in[5];
    const float* Wk   = (const float*)d_in[6];  const float* bk  = (const float*)d_in[7];
    const float* Wv   = (const float*)d_in[8];  const float* bv  = (const float*)d_in[9];
    const float* Wo   = (const float*)d_in[10]; const float* bo  = (const float*)d_in[11];
    const float* lng  = (const float*)d_in[12]; const float* lnb = (const float*)d_in[13];
    const float* Wp   = (const float*)d_in[14]; const float* bp  = (const float*)d_in[15];
    const float* Wih0 = (const float*)d_in[16]; const float* Whh0 = (const float*)d_in[17];
    const float* bih0 = (const float*)d_in[18]; const float* bhh0 = (const float*)d_in[19];
    const float* Wih1 = (const float*)d_in[20]; const float* Whh1 = (const float*)d_in[21];
    const float* bih1 = (const float*)d_in[22]; const float* bhh1 = (const float*)d_in[23];
    const float* Wout = (const float*)d_in[24]; const float* bout = (const float*)d_in[25];
    float* out = (float*)d_out;

    const size_t S_BH = (size_t)BZ * HS;                 // 196608
    const size_t S_KV = (size_t)BZ * MCN * HS;           // 25.17M elems

    float* w = (float*)d_ws;
    size_t off = 0;
    auto alloc = [&](size_t n) { off = (off + 3) & ~(size_t)3; float* p = w + off; off += n; return p; };
    ushort* Kbf   = (ushort*)alloc(S_KV / 2);            // bf16 K'
    ushort* Vbf   = (ushort*)alloc(S_KV / 2);            // bf16 V'
    float*  cmask = alloc((size_t)BZ * MCN);
    ushort* W0xbf = (ushort*)alloc((size_t)G4 * HS / 2); // bf16 Wih0@WpA
    ushort* W0cbf = (ushort*)alloc((size_t)G4 * HS / 2); // bf16 Wih0@WpC
    float*  WkqT  = alloc((size_t)HS * HS);              // = 3*S_BH; reused for h1a/h0a/attn
    float*  WvoT  = alloc((size_t)HS * HS);              // = 3*S_BH; reused for h1b/h0b/c0
    float*  c1    = alloc(S_BH);
    float*  T7    = alloc((size_t)NC * HS);
    float*  T7g   = alloc((size_t)NC * G4);
    float*  bp0   = alloc(G4);
    float*  bc1   = alloc(G4);
    float*  bkq   = alloc(HS);
    float*  bvo   = alloc(HS);
    float*  kqv   = alloc(HS + 1);
    // step-time aliases over WkqT/WvoT (dead after K'/V' precompute)
    float* h1a  = WkqT;
    float* h0a  = WkqT + S_BH;
    float* attn = WkqT + 2 * S_BH;
    float* h1b  = WvoT;
    float* h0b  = WvoT + S_BH;
    float* c0   = WvoT + 2 * S_BH;

    const float scale = 1.0f / sqrtf((float)HS);
    dim3 blk(256);

    // ---- folds ----
    t7_kernel<<<(NC * HS + 255) / 256, 256, 0, stream>>>(LE, Wp, T7);
    gemm_atb<<<dim3(12, 12), blk, 0, stream>>>(Wq, HS, Wk, HS, WkqT, HS, HS, scale);
    gemm_ab <<<dim3(12, 12), blk, 0, stream>>>(Wo, HS, Wv, HS, WvoT, nullptr, HS, HS);
    gemm_ab <<<dim3(12, 48), blk, 0, stream>>>(Wih0, HS, Wp + LED,      LDP, nullptr, W0xbf, HS, HS);
    gemm_ab <<<dim3(12, 48), blk, 0, stream>>>(Wih0, HS, Wp + LED + HS, LDP, nullptr, W0cbf, HS, HS);
    fold_vecs<<<4, 256, 0, stream>>>(Wq, Wk, Wo, bq, bk, bv, bkq, bvo, kqv, scale);
    cmask_kernel<<<(BZ * MCN) / 4, 256, 0, stream>>>(cv, mask, kqv, cmask);
    t7g_bp0<<<12, 256, 0, stream>>>(T7, Wih0, bp, bih0, bhh0, T7g, bp0);
    vec_add2<<<12, 256, 0, stream>>>(bih1, bhh1, bc1);
    // ---- big precompute GEMMs (bf16 out) ----
    gemm_abt<<<dim3(12, (BZ * MCN) / TBM), blk, 0, stream>>>(cv, HS, WkqT, HS, bkq, nullptr, Kbf, HS, HS);
    gemm_abt<<<dim3(12, (BZ * MCN) / TBM), blk, 0, stream>>>(cv, HS, WvoT, HS, bvo, nullptr, Vbf, HS, HS);
    // ---- zero h/c state (aliases over WkqT/WvoT; stream-ordered after the GEMMs) ----
    hipMemsetAsync(WkqT, 0, 7 * S_BH * sizeof(float), stream);   // h1a,h0a,attn,h1b,h0b,c0,c1

    // ---- serial decode loop: 3 kernels/step ----
    for (int t = 0; t < MCN; ++t) {
        const float* h0r = (t & 1) ? h0b : h0a;  float* h0w = (t & 1) ? h0a : h0b;
        const float* h1r = (t & 1) ? h1b : h1a;  float* h1w = (t & 1) ? h1a : h1b;
        attn_step<<<BZ, 768, 0, stream>>>(h1r, Kbf, Vbf, cmask, lng, lnb, bo,
                                          Wout, bout, out, attn, t);
        // lstm0: gates = attn@W0x^T + cv_t@W0c^T + h0@Whh0^T + bp0 + emb
        lstm_fused<<<dim3(24, 8), blk, 0, stream>>>(
            attn, (long)HS, W0xbf, 1,
            cv + (size_t)t * HS, (long)MCN * HS, W0cbf, 1,
            h0r, (long)HS, Whh0, 0, 3,
            bp0, tl, T7g, t, c0, h0w);
        // lstm1: gates = h0@Wih1^T + h1@Whh1^T + bc1
        lstm_fused<<<dim3(24, 8), blk, 0, stream>>>(
            h0w, (long)HS, Wih1, 0,
            h1r, (long)HS, Whh1, 0,
            nullptr, 0, nullptr, 0, 2,
            bc1, nullptr, nullptr, 0, c1, h1w);
    }
    pred_kernel<<<dim3(BZ, NC), 64, 0, stream>>>(h1a, Wout, bout, out, MCN - 1);
}